// Round 5
// baseline (2191.202 us; speedup 1.0000x reference)
//
#include <hip/hip_runtime.h>
#include <hip/hip_bf16.h>
#include <stdint.h>

#define N_NODES 20000
#define N_EDGES 40000
#define NODE_DIM 5
#define EDGE_DIM 6
#define HID 64
#define N_GRAPHS 500
#define NPG 40
#define TORSIONS 10
#define N_TORS (N_GRAPHS * TORSIONS)
#define ACT 6

typedef short short8 __attribute__((ext_vector_type(8)));
typedef float f32x4 __attribute__((ext_vector_type(4)));

__device__ __forceinline__ float sigmoidf_(float x) { return 1.0f / (1.0f + __expf(-x)); }
__device__ __forceinline__ float dot4(float4 a, float4 b) {
    return a.x * b.x + a.y * b.y + a.z * b.z + a.w * b.w;
}
__device__ __forceinline__ short8 pack_bf8(float4 a, float4 b) {
    union { short8 s; __hip_bfloat16 h[8]; } u;
    u.h[0] = __float2bfloat16(a.x); u.h[1] = __float2bfloat16(a.y);
    u.h[2] = __float2bfloat16(a.z); u.h[3] = __float2bfloat16(a.w);
    u.h[4] = __float2bfloat16(b.x); u.h[5] = __float2bfloat16(b.y);
    u.h[6] = __float2bfloat16(b.z); u.h[7] = __float2bfloat16(b.w);
    return u.s;
}

// ---------------- lin0 ----------------
__global__ void k_lin0(const float* __restrict__ x, const float* __restrict__ w,
                       const float* __restrict__ b, float* __restrict__ out) {
    int i = blockIdx.x * blockDim.x + threadIdx.x;
    int n = i >> 6, k = i & 63;
    const float* xr = x + n * NODE_DIM;
    const float* wr = w + k * NODE_DIM;
    float s = b[k];
#pragma unroll
    for (int d = 0; d < NODE_DIM; ++d) s += xr[d] * wr[d];
    out[i] = fmaxf(s, 0.0f);
}

// ---------------- h1 ----------------
__global__ void k_h1(const float* __restrict__ ea, const float* __restrict__ w1,
                     const float* __restrict__ b1, __hip_bfloat16* __restrict__ h1b) {
    int i = blockIdx.x * blockDim.x + threadIdx.x;
    int e = i >> 7, j = i & 127;
    const float* er = ea + e * EDGE_DIM;
    const float* wr = w1 + j * EDGE_DIM;
    float s = b1[j];
#pragma unroll
    for (int d = 0; d < EDGE_DIM; ++d) s += er[d] * wr[d];
    h1b[i] = __float2bfloat16(fmaxf(s, 0.0f));
}

// ------- W2 permute rows (cp = k*64+h <- c = h*64+k) + bf16; bias bf16 -------
__global__ void k_prep(const float* __restrict__ w2, const float* __restrict__ b2,
                       __hip_bfloat16* __restrict__ w2pb, __hip_bfloat16* __restrict__ b2pb) {
    int i = blockIdx.x * blockDim.x + threadIdx.x;
    int cp = i >> 7, j = i & 127;
    int c = ((cp & 63) << 6) | (cp >> 6);
    w2pb[i] = __float2bfloat16(w2[c * 128 + j]);
    if (j == 0) b2pb[cp] = __float2bfloat16(b2[c]);
}

// ------- GRU / conv weights to bf16 -------
__global__ void k_prep2(const float* __restrict__ cr, const float* __restrict__ wih,
                        const float* __restrict__ whh,
                        __hip_bfloat16* __restrict__ crTb, __hip_bfloat16* __restrict__ wihb,
                        __hip_bfloat16* __restrict__ whhb) {
    int i = blockIdx.x * blockDim.x + threadIdx.x;
    if (i < 12288) {
        wihb[i] = __float2bfloat16(wih[i]);
    } else if (i < 24576) {
        whhb[i - 12288] = __float2bfloat16(whh[i - 12288]);
    } else if (i < 24576 + 4096) {
        int t = i - 24576;
        int c = t >> 6, h = t & 63;
        crTb[t] = __float2bfloat16(cr[h * 64 + c]);
    }
}

// ---------------- degree ----------------
__global__ void k_deg(const int* __restrict__ ei, float* __restrict__ deg) {
    int e = blockIdx.x * blockDim.x + threadIdx.x;
    if (e >= N_EDGES) return;
    atomicAdd(&deg[ei[N_EDGES + e]], 1.0f);
}

// ---- edge compute chunk: CE edges-of-16 groups, MFMA from LDS, reduce+atomic ----
template<int CE>
__device__ __forceinline__ void edge_chunk(
    int ec, int lm, int lk, int w, int kt,
    const short8* __restrict__ aSb8, const float4* __restrict__ oS4,
    const short8 afr[4][4], const f32x4* __restrict__ bc,
    const int* __restrict__ dstS, float* __restrict__ agg) {
    short8 bfr[CE][4];
#pragma unroll
    for (int ce = 0; ce < CE; ++ce)
#pragma unroll
        for (int ks = 0; ks < 4; ++ks)
            bfr[ce][ks] = aSb8[((ec * 4 + ce) * 16 + lm) * 17 + ks * 4 + lk];
    float pacc[CE];
#pragma unroll
    for (int ce = 0; ce < CE; ++ce) pacc[ce] = 0.f;
#pragma unroll
    for (int hi = 0; hi < 4; ++hi) {
        f32x4 acc[CE];
#pragma unroll
        for (int ce = 0; ce < CE; ++ce) acc[ce] = (f32x4){0.f, 0.f, 0.f, 0.f};
#pragma unroll
        for (int ks = 0; ks < 4; ++ks)
#pragma unroll
            for (int ce = 0; ce < CE; ++ce)
                acc[ce] = __builtin_amdgcn_mfma_f32_16x16x32_bf16(afr[hi][ks], bfr[ce][ks], acc[ce], 0, 0, 0);
#pragma unroll
        for (int ce = 0; ce < CE; ++ce) {
            float4 o = oS4[((ec * 4 + ce) * 16 + lm) * 17 + hi * 4 + lk];
            pacc[ce] += acc[ce][0] * o.x + acc[ce][1] * o.y + acc[ce][2] * o.z + acc[ce][3] * o.w;
        }
    }
#pragma unroll
    for (int ce = 0; ce < CE; ++ce) {
        int ee = ec * 4 + ce;
        float p = pacc[ce] + ((lk == 0) ? bc[ee][w] : 0.f);
        p += __shfl_xor(p, 16);
        p += __shfl_xor(p, 32);
        if (lk == 0) atomicAdd(&agg[(size_t)dstS[ee * 16 + lm] * 64 + kt], p);
    }
}

// ---------------- fused edge-weight GEMM + message + aggregation ----------------
// grid = 250 edge-tiles(160) x 16 k-splits(4 kt). All MFMA operands from LDS.
__global__ __launch_bounds__(256) void k_edge_fused(
    const int* __restrict__ ei, const float* __restrict__ out,
    const __hip_bfloat16* __restrict__ h1b, const __hip_bfloat16* __restrict__ w2pb,
    const __hip_bfloat16* __restrict__ b2pb, float* __restrict__ agg) {
    __shared__ __align__(16) short aS[160 * 17 * 8];     // h1 rows, stride 17 short8 (43.5 KB)
    __shared__ __align__(16) short w2S[4 * 64 * 17 * 8]; // W2 slice, stride 17 short8 (69.6 KB)
    __shared__ __align__(16) float oS[160 * 68];         // out[src] rows, stride 68 f32 (43.5 KB)
    __shared__ int dstS[160];
    int eb = blockIdx.x >> 4, kb = blockIdx.x & 15;
    int e0 = eb * 160;
    int tid = threadIdx.x, w = tid >> 6, lane = tid & 63;
    {   // stage h1: 160 rows x 16 short8
        const uint4* g = (const uint4*)(h1b + (size_t)e0 * 128);
        uint4* s = (uint4*)aS;
        for (int i = tid; i < 160 * 16; i += 256) {
            int r = i >> 4, c = i & 15;
            s[r * 17 + c] = g[i];
        }
    }
    {   // stage W2 slice: rows kb*256 .. +256 of w2pb (contiguous)
        const uint4* g = (const uint4*)(w2pb + (size_t)kb * 256 * 128);
        uint4* s = (uint4*)w2S;
        for (int i = tid; i < 256 * 16; i += 256) {
            int r = i >> 4, c = i & 15;
            s[r * 17 + c] = g[i];
        }
    }
    {   // gather out[src] rows + dst indices
        const float4* og = (const float4*)out;
        float4* s = (float4*)oS;
        for (int i = tid; i < 160 * 16; i += 256) {
            int r = i >> 4, q = i & 15;
            int src = ei[e0 + r];
            s[r * 17 + q] = og[(size_t)src * 16 + q];
        }
        if (tid < 160) dstS[tid] = ei[N_EDGES + e0 + tid];
    }
    __syncthreads();
    int lm = lane & 15, lk = lane >> 4;
    int kt = (kb << 2) + w;
    const short8* aSb8 = (const short8*)aS;
    const short8* wSb8 = (const short8*)w2S;
    const float4* oS4 = (const float4*)oS;
    // cache this wave's 16 A-fragments (its kt's W2 rows)
    short8 afr[4][4];
#pragma unroll
    for (int hi = 0; hi < 4; ++hi)
#pragma unroll
        for (int ks = 0; ks < 4; ++ks)
            afr[hi][ks] = wSb8[(w * 64 + hi * 16 + lm) * 17 + ks * 4 + lk];
    // bias tile: bc[ee][j]: row j -> kt_local j, col lm -> edge ee*16+lm
    f32x4 bc[10];
#pragma unroll
    for (int ee = 0; ee < 10; ++ee) bc[ee] = (f32x4){0.f, 0.f, 0.f, 0.f};
    {
        const short8* BP = (const short8*)b2pb;
#pragma unroll
        for (int ks = 0; ks < 2; ++ks) {
            short8 ab = BP[((kb << 2) + (lm & 3)) * 8 + ks * 4 + lk];
#pragma unroll
            for (int ee = 0; ee < 10; ++ee) {
                int e = ee * 16 + lm;
                float4 f0 = oS4[e * 17 + ks * 8 + lk * 2];
                float4 f1 = oS4[e * 17 + ks * 8 + lk * 2 + 1];
                bc[ee] = __builtin_amdgcn_mfma_f32_16x16x32_bf16(ab, pack_bf8(f0, f1), bc[ee], 0, 0, 0);
            }
        }
    }
    edge_chunk<4>(0, lm, lk, w, kt, aSb8, oS4, afr, bc, dstS, agg);
    edge_chunk<4>(1, lm, lk, w, kt, aSb8, oS4, afr, bc, dstS, agg);
    edge_chunk<2>(2, lm, lk, w, kt, aSb8, oS4, afr, bc, dstS, agg);
}

// ---------------- fused node update: 1 wave = 16 nodes; root GEMM + m + GRU ----------------
__global__ __launch_bounds__(64) void k_node_fused(
    float* __restrict__ out, float* __restrict__ agg, const float* __restrict__ deg,
    const __hip_bfloat16* __restrict__ crTb, const float* __restrict__ cb,
    const __hip_bfloat16* __restrict__ wihb, const __hip_bfloat16* __restrict__ whhb,
    const float* __restrict__ bih, const float* __restrict__ bhh) {
    __shared__ __align__(16) float Xf[16 * 68];
    __shared__ __align__(16) short Xb[16 * 72];
    __shared__ __align__(16) short Mb[16 * 72];
    int n0 = blockIdx.x << 4;
    int lane = threadIdx.x;
    {
        int r = lane >> 2, q = lane & 3;
        const float4* gv = (const float4*)(out + (size_t)(n0 + r) * 64);
        float4 v[4];
#pragma unroll
        for (int i = 0; i < 4; ++i) v[i] = gv[q * 4 + i];
        float4* sv = (float4*)Xf;
#pragma unroll
        for (int i = 0; i < 4; ++i) sv[r * 17 + q * 4 + i] = v[i];
        __hip_bfloat16* xb = (__hip_bfloat16*)Xb;
        const float* vf = (const float*)v;
#pragma unroll
        for (int i = 0; i < 16; ++i) xb[r * 72 + q * 16 + i] = __float2bfloat16(vf[i]);
    }
    __syncthreads();
    int lm = lane & 15, lk = lane >> 4;
    const short8* Xb8 = (const short8*)Xb;
    short8 ax[2];
#pragma unroll
    for (int ks = 0; ks < 2; ++ks) ax[ks] = Xb8[lm * 9 + ks * 4 + lk];
    const short8* Bc = (const short8*)crTb;
    f32x4 accr[4];
#pragma unroll
    for (int ci = 0; ci < 4; ++ci) accr[ci] = (f32x4){0.f, 0.f, 0.f, 0.f};
#pragma unroll
    for (int ks = 0; ks < 2; ++ks)
#pragma unroll
        for (int ci = 0; ci < 4; ++ci) {
            short8 b = Bc[(ci * 16 + lm) * 8 + ks * 4 + lk];
            accr[ci] = __builtin_amdgcn_mfma_f32_16x16x32_bf16(ax[ks], b, accr[ci], 0, 0, 0);
        }
    __hip_bfloat16* mb = (__hip_bfloat16*)Mb;
#pragma unroll
    for (int ci = 0; ci < 4; ++ci) {
        int col = ci * 16 + lm;
        float cbv = cb[col];
#pragma unroll
        for (int j = 0; j < 4; ++j) {
            int row = lk * 4 + j;
            int n = n0 + row;
            float a = agg[(size_t)n * 64 + col];
            agg[(size_t)n * 64 + col] = 0.0f;
            float d = fmaxf(deg[n], 1.f);
            float m = fmaxf(a / d + accr[ci][j] + cbv, 0.f);
            mb[row * 72 + col] = __float2bfloat16(m);
        }
    }
    __syncthreads();
    short8 am[2];
#pragma unroll
    for (int ks = 0; ks < 2; ++ks) am[ks] = ((const short8*)Mb)[lm * 9 + ks * 4 + lk];
    const short8* Bi = (const short8*)wihb;
    const short8* Bh = (const short8*)whhb;
    f32x4 gi[12], gh[12];
#pragma unroll
    for (int ci = 0; ci < 12; ++ci) {
        gi[ci] = (f32x4){0.f, 0.f, 0.f, 0.f};
        gh[ci] = (f32x4){0.f, 0.f, 0.f, 0.f};
    }
#pragma unroll
    for (int ks = 0; ks < 2; ++ks)
#pragma unroll
        for (int ci = 0; ci < 12; ++ci) {
            short8 bi = Bi[(ci * 16 + lm) * 8 + ks * 4 + lk];
            short8 bh = Bh[(ci * 16 + lm) * 8 + ks * 4 + lk];
            gi[ci] = __builtin_amdgcn_mfma_f32_16x16x32_bf16(am[ks], bi, gi[ci], 0, 0, 0);
            gh[ci] = __builtin_amdgcn_mfma_f32_16x16x32_bf16(ax[ks], bh, gh[ci], 0, 0, 0);
        }
#pragma unroll
    for (int ci = 0; ci < 4; ++ci) {
        int col = ci * 16 + lm;
        float bir = bih[col], biz = bih[64 + col], bin = bih[128 + col];
        float bhr = bhh[col], bhz = bhh[64 + col], bhn = bhh[128 + col];
#pragma unroll
        for (int j = 0; j < 4; ++j) {
            int row = lk * 4 + j;
            int n = n0 + row;
            float r = sigmoidf_(gi[ci][j] + bir + gh[ci][j] + bhr);
            float z = sigmoidf_(gi[ci + 4][j] + biz + gh[ci + 4][j] + bhz);
            float nn = tanhf(gi[ci + 8][j] + bin + r * (gh[ci + 8][j] + bhn));
            float hold = Xf[row * 68 + col];
            out[(size_t)n * 64 + col] = (1.f - z) * nn + z * hold;
        }
    }
}

// ---------------- Set2Set (6 steps) + memory LSTM ----------------
__global__ __launch_bounds__(64) void k_s2s(const float* __restrict__ out,
                                            const float* __restrict__ wih, const float* __restrict__ whh,
                                            const float* __restrict__ bih, const float* __restrict__ bhh,
                                            const float* __restrict__ mwih, const float* __restrict__ mbih,
                                            const float* __restrict__ mbhh,
                                            float* __restrict__ dout, float* __restrict__ hx_buf) {
    int g = blockIdx.x;
    int lane = threadIdx.x;
    __shared__ __align__(16) float os[NPG][65];
    __shared__ __align__(16) float q[128];
    __shared__ __align__(16) float hsS[64];
    __shared__ __align__(16) float aS[NPG];
    for (int n = 0; n < NPG; ++n) os[n][lane] = out[(size_t)(g * NPG + n) * 64 + lane];
    q[lane] = 0.0f;
    q[64 + lane] = 0.0f;
    hsS[lane] = 0.0f;
    float cs = 0.0f;
    __syncthreads();
    const float4* qv = (const float4*)q;
    const float4* hv = (const float4*)hsS;
    for (int step = 0; step < 6; ++step) {
        float gate[4];
#pragma unroll
        for (int gg = 0; gg < 4; ++gg) {
            int j = gg * 64 + lane;
            const float4* wr = (const float4*)(wih + (size_t)j * 128);
            const float4* vr = (const float4*)(whh + (size_t)j * 64);
            float s = bih[j] + bhh[j];
#pragma unroll 8
            for (int i = 0; i < 32; ++i) s += dot4(qv[i], wr[i]);
#pragma unroll 8
            for (int i = 0; i < 16; ++i) s += dot4(hv[i], vr[i]);
            gate[gg] = s;
        }
        cs = sigmoidf_(gate[1]) * cs + sigmoidf_(gate[0]) * tanhf(gate[2]);
        float hsv = sigmoidf_(gate[3]) * tanhf(cs);
        __syncthreads();
        hsS[lane] = hsv;
        __syncthreads();
        float e_n = -INFINITY;
        if (lane < NPG) {
            float s = 0.0f;
            for (int h = 0; h < 64; ++h) s += os[lane][h] * hsS[h];
            e_n = s;
        }
        float mx = e_n;
#pragma unroll
        for (int off = 32; off; off >>= 1) mx = fmaxf(mx, __shfl_xor(mx, off));
        float ex = (lane < NPG) ? __expf(e_n - mx) : 0.0f;
        float sm = ex;
#pragma unroll
        for (int off = 32; off; off >>= 1) sm += __shfl_xor(sm, off);
        if (lane < NPG) aS[lane] = ex / sm;
        __syncthreads();
        float r = 0.0f;
        for (int n = 0; n < NPG; ++n) r += aS[n] * os[n][lane];
        __syncthreads();
        q[lane] = hsv;
        q[64 + lane] = r;
        __syncthreads();
    }
    float gate[4];
#pragma unroll
    for (int gg = 0; gg < 4; ++gg) {
        int j = gg * 64 + lane;
        const float4* wr = (const float4*)(mwih + (size_t)j * 128);
        float s = mbih[j] + mbhh[j];
#pragma unroll 8
        for (int i = 0; i < 32; ++i) s += dot4(qv[i], wr[i]);
        gate[gg] = s;
    }
    float cx = sigmoidf_(gate[0]) * tanhf(gate[2]);
    float hx = sigmoidf_(gate[3]) * tanhf(cx);
    dout[30000 + g * 64 + lane] = hx;
    dout[62000 + g * 64 + lane] = cx;
    hx_buf[g * 64 + lane] = hx;
}

// ---------------- final MLP over torsions ----------------
__global__ __launch_bounds__(256) void k_mlp(const float* __restrict__ out,
                                             const float* __restrict__ hx_buf,
                                             const int* __restrict__ nrbidx,
                                             const int* __restrict__ nonring,
                                             const float* __restrict__ w1, const float* __restrict__ b1,
                                             const float* __restrict__ w2, const float* __restrict__ b2,
                                             float* __restrict__ logits) {
    __shared__ __align__(16) float feat[4][320];
    __shared__ __align__(16) float hid[4][64];
    int w = threadIdx.x >> 6, lane = threadIdx.x & 63;
    int t = (blockIdx.x << 2) + w;
    int g = nrbidx[t];
    feat[w][lane] = hx_buf[g * 64 + lane];
#pragma unroll
    for (int i = 0; i < 4; ++i) {
        int node = nonring[t * 4 + i];
        feat[w][64 + i * 64 + lane] = out[(size_t)node * 64 + lane];
    }
    __syncthreads();
    const float4* fv = (const float4*)feat[w];
    const float4* wr = (const float4*)(w1 + (size_t)lane * 320);
    float s = b1[lane];
#pragma unroll 8
    for (int i = 0; i < 80; ++i) s += dot4(fv[i], wr[i]);
    hid[w][lane] = fmaxf(s, 0.0f);
    __syncthreads();
    if (lane < ACT) {
        const float* hr = hid[w];
        const float* w2r = w2 + lane * 64;
        float s2 = b2[lane];
#pragma unroll 8
        for (int k = 0; k < 64; ++k) s2 += hr[k] * w2r[k];
        logits[t * ACT + lane] = s2;
    }
}

static inline size_t align256(size_t x) { return (x + 255) & ~(size_t)255; }

extern "C" void kernel_launch(void* const* d_in, const int* in_sizes, int n_in,
                              void* d_out, int out_size, void* d_ws, size_t ws_size,
                              hipStream_t stream) {
    const float* x         = (const float*)d_in[0];
    const float* edge_attr = (const float*)d_in[1];
    const int*   edge_index= (const int*)d_in[2];
    const int*   nrbidx    = (const int*)d_in[4];
    const int*   nonring   = (const int*)d_in[5];
    const float* lin0_w    = (const float*)d_in[6];
    const float* lin0_b    = (const float*)d_in[7];
    const float* enn_w1    = (const float*)d_in[8];
    const float* enn_b1    = (const float*)d_in[9];
    const float* enn_w2    = (const float*)d_in[10];
    const float* enn_b2    = (const float*)d_in[11];
    const float* conv_root = (const float*)d_in[12];
    const float* conv_bias = (const float*)d_in[13];
    const float* gru_wih   = (const float*)d_in[14];
    const float* gru_whh   = (const float*)d_in[15];
    const float* gru_bih   = (const float*)d_in[16];
    const float* gru_bhh   = (const float*)d_in[17];
    const float* s2s_wih   = (const float*)d_in[18];
    const float* s2s_whh   = (const float*)d_in[19];
    const float* s2s_bih   = (const float*)d_in[20];
    const float* s2s_bhh   = (const float*)d_in[21];
    const float* mem_wih   = (const float*)d_in[22];
    const float* mem_bih   = (const float*)d_in[24];
    const float* mem_bhh   = (const float*)d_in[25];
    const float* mlp_w1    = (const float*)d_in[26];
    const float* mlp_b1    = (const float*)d_in[27];
    const float* mlp_w2    = (const float*)d_in[28];
    const float* mlp_b2    = (const float*)d_in[29];
    float* dout = (float*)d_out;

    char* ws = (char*)d_ws;
    size_t off = 0;
    float* out_buf = (float*)(ws + off); off = align256(off + (size_t)N_NODES * 64 * 4);
    float* agg     = (float*)(ws + off); off = align256(off + (size_t)N_NODES * 64 * 4);
    __hip_bfloat16* h1b  = (__hip_bfloat16*)(ws + off); off = align256(off + (size_t)N_EDGES * 128 * 2);
    __hip_bfloat16* w2pb = (__hip_bfloat16*)(ws + off); off = align256(off + (size_t)4096 * 128 * 2);
    __hip_bfloat16* b2pb = (__hip_bfloat16*)(ws + off); off = align256(off + 4096 * 2);
    float* deg     = (float*)(ws + off); off = align256(off + N_NODES * 4);
    float* hx_buf  = (float*)(ws + off); off = align256(off + (size_t)N_GRAPHS * 64 * 4);
    __hip_bfloat16* wihb = (__hip_bfloat16*)(ws + off); off = align256(off + 192 * 64 * 2);
    __hip_bfloat16* whhb = (__hip_bfloat16*)(ws + off); off = align256(off + 192 * 64 * 2);
    __hip_bfloat16* crTb = (__hip_bfloat16*)(ws + off); off = align256(off + 64 * 64 * 2);
    if (ws_size < off) return;

    k_lin0<<<(N_NODES * 64) / 256, 256, 0, stream>>>(x, lin0_w, lin0_b, out_buf);
    k_h1<<<(N_EDGES * 128) / 256, 256, 0, stream>>>(edge_attr, enn_w1, enn_b1, h1b);
    k_prep<<<(4096 * 128) / 256, 256, 0, stream>>>(enn_w2, enn_b2, w2pb, b2pb);
    k_prep2<<<112, 256, 0, stream>>>(conv_root, gru_wih, gru_whh, crTb, wihb, whhb);
    hipMemsetAsync(deg, 0, N_NODES * 4, stream);
    k_deg<<<(N_EDGES + 255) / 256, 256, 0, stream>>>(edge_index, deg);
    hipMemsetAsync(agg, 0, (size_t)N_NODES * 64 * 4, stream);
    for (int it = 0; it < 6; ++it) {
        k_edge_fused<<<250 * 16, 256, 0, stream>>>(edge_index, out_buf, h1b, w2pb, b2pb, agg);
        k_node_fused<<<N_NODES / 16, 64, 0, stream>>>(out_buf, agg, deg, crTb, conv_bias,
                                                      wihb, whhb, gru_bih, gru_bhh);
    }
    k_s2s<<<N_GRAPHS, 64, 0, stream>>>(out_buf, s2s_wih, s2s_whh, s2s_bih, s2s_bhh,
                                       mem_wih, mem_bih, mem_bhh, dout, hx_buf);
    k_mlp<<<N_TORS / 4, 256, 0, stream>>>(out_buf, hx_buf, nrbidx, nonring,
                                          mlp_w1, mlp_b1, mlp_w2, mlp_b2, dout);
}

// Round 6
// 913.897 us; speedup vs baseline: 2.3976x; 2.3976x over previous
//
#include <hip/hip_runtime.h>
#include <hip/hip_bf16.h>
#include <stdint.h>

#define N_NODES 20000
#define N_EDGES 40000
#define NODE_DIM 5
#define EDGE_DIM 6
#define HID 64
#define N_GRAPHS 500
#define NPG 40
#define TORSIONS 10
#define N_TORS (N_GRAPHS * TORSIONS)
#define ACT 6

typedef short short8 __attribute__((ext_vector_type(8)));
typedef float f32x4 __attribute__((ext_vector_type(4)));

__device__ __forceinline__ float sigmoidf_(float x) { return 1.0f / (1.0f + __expf(-x)); }
__device__ __forceinline__ float dot4(float4 a, float4 b) {
    return a.x * b.x + a.y * b.y + a.z * b.z + a.w * b.w;
}

// ---------------- lin0 ----------------
__global__ void k_lin0(const float* __restrict__ x, const float* __restrict__ w,
                       const float* __restrict__ b, float* __restrict__ out) {
    int i = blockIdx.x * blockDim.x + threadIdx.x;
    int n = i >> 6, k = i & 63;
    const float* xr = x + n * NODE_DIM;
    const float* wr = w + k * NODE_DIM;
    float s = b[k];
#pragma unroll
    for (int d = 0; d < NODE_DIM; ++d) s += xr[d] * wr[d];
    out[i] = fmaxf(s, 0.0f);
}

// ---------------- h1 ----------------
__global__ void k_h1(const float* __restrict__ ea, const float* __restrict__ w1,
                     const float* __restrict__ b1, __hip_bfloat16* __restrict__ h1b) {
    int i = blockIdx.x * blockDim.x + threadIdx.x;
    int e = i >> 7, j = i & 127;
    const float* er = ea + e * EDGE_DIM;
    const float* wr = w1 + j * EDGE_DIM;
    float s = b1[j];
#pragma unroll
    for (int d = 0; d < EDGE_DIM; ++d) s += er[d] * wr[d];
    h1b[i] = __float2bfloat16(fmaxf(s, 0.0f));
}

// ------- W2 permute rows (cp = k*64+h <- c = h*64+k) + bf16; bias bf16 -------
__global__ void k_prep(const float* __restrict__ w2, const float* __restrict__ b2,
                       __hip_bfloat16* __restrict__ w2pb, __hip_bfloat16* __restrict__ b2pb) {
    int i = blockIdx.x * blockDim.x + threadIdx.x;
    int cp = i >> 7, j = i & 127;
    int c = ((cp & 63) << 6) | (cp >> 6);
    w2pb[i] = __float2bfloat16(w2[c * 128 + j]);
    if (j == 0) b2pb[cp] = __float2bfloat16(b2[c]);
}

// ------- GRU / conv weights to bf16 -------
__global__ void k_prep2(const float* __restrict__ cr, const float* __restrict__ wih,
                        const float* __restrict__ whh,
                        __hip_bfloat16* __restrict__ crTb, __hip_bfloat16* __restrict__ wihb,
                        __hip_bfloat16* __restrict__ whhb) {
    int i = blockIdx.x * blockDim.x + threadIdx.x;
    if (i < 12288) {
        wihb[i] = __float2bfloat16(wih[i]);
    } else if (i < 24576) {
        whhb[i - 12288] = __float2bfloat16(whh[i - 12288]);
    } else if (i < 24576 + 4096) {
        int t = i - 24576;
        int c = t >> 6, h = t & 63;
        crTb[t] = __float2bfloat16(cr[h * 64 + c]);
    }
}

// ---------------- in-degree (int) ----------------
__global__ void k_deg(const int* __restrict__ ei, int* __restrict__ degi) {
    int e = blockIdx.x * blockDim.x + threadIdx.x;
    if (e >= N_EDGES) return;
    atomicAdd(&degi[ei[N_EDGES + e]], 1);
}

// ---------------- exclusive scan -> rowptr, cursor (one block) ----------------
#define SCAN_C 79  // 256*79 = 20224 >= 20000
__global__ __launch_bounds__(256) void k_scan(const int* __restrict__ degi,
                                              int* __restrict__ rowptr, int* __restrict__ cursor) {
    __shared__ int part[256];
    int t = threadIdx.x;
    int base = t * SCAN_C;
    int s = 0;
    for (int i = 0; i < SCAN_C; ++i) {
        int idx = base + i;
        if (idx < N_NODES) s += degi[idx];
    }
    part[t] = s;
    __syncthreads();
    for (int off = 1; off < 256; off <<= 1) {
        int v = (t >= off) ? part[t - off] : 0;
        __syncthreads();
        part[t] += v;
        __syncthreads();
    }
    int run = part[t] - s;  // exclusive prefix
    for (int i = 0; i < SCAN_C; ++i) {
        int idx = base + i;
        if (idx < N_NODES) {
            rowptr[idx] = run;
            cursor[idx] = run;
            run += degi[idx];
        }
    }
    if (t == 0) rowptr[N_NODES] = N_EDGES;
}

// ---------------- CSR fill ----------------
__global__ void k_fill(const int* __restrict__ ei, int* __restrict__ cursor,
                       int* __restrict__ csr) {
    int e = blockIdx.x * blockDim.x + threadIdx.x;
    if (e >= N_EDGES) return;
    int d = ei[N_EDGES + e];
    int pos = atomicAdd(&cursor[d], 1);
    csr[pos] = e;
}

// ---------------- edge messages: msg[e][kt] = (W2_kt @ h1_e + b2_kt) . out[src_e] ----------------
// grid = 125 edge-groups x 16 kt-blocks (blockIdx = ebg*16+kb, consecutive kb share tiles -> L2 hot).
// Block: 4 waves, wave w owns kt = kb*4+w; its W2 slice (64x128) lives in 64 VGPRs, loaded once.
// Loops over 5 edge-tiles of 64: stage h1+o in LDS, 16 MFMA per ee-group, in-register dot, 2 shfl, plain store.
#define EPB 5
__global__ __launch_bounds__(256) void k_edge_msg(
    const int* __restrict__ ei, const float* __restrict__ out,
    const __hip_bfloat16* __restrict__ h1b, const __hip_bfloat16* __restrict__ w2pb,
    const __hip_bfloat16* __restrict__ b2pb, float* __restrict__ msg) {
    __shared__ __align__(16) short aS[64 * 17 * 8];   // h1 rows, stride 17 short8 (34.8 KB)
    __shared__ __align__(16) float oS[64 * 68];       // o rows, stride 68 f32 (17.4 KB)
    int ebg = blockIdx.x >> 4, kb = blockIdx.x & 15;
    int tid = threadIdx.x, w = tid >> 6, lane = tid & 63;
    int lm = lane & 15, lk = lane >> 4;
    int kt = (kb << 2) + w;
    // W2 A-fragments from global (L2-resident 1 MB), once per block
    const short8* W8 = (const short8*)w2pb;
    short8 afr[4][4];
#pragma unroll
    for (int hi = 0; hi < 4; ++hi)
#pragma unroll
        for (int ks = 0; ks < 4; ++ks)
            afr[hi][ks] = W8[(size_t)(kt * 64 + hi * 16 + lm) * 16 + ks * 4 + lk];
    // bias values for this lane's C-frag rows: h = hi*16 + lk*4 + j
    float bb[4][4];
#pragma unroll
    for (int hi = 0; hi < 4; ++hi)
#pragma unroll
        for (int j = 0; j < 4; ++j)
            bb[hi][j] = __bfloat162float(b2pb[kt * 64 + hi * 16 + lk * 4 + j]);
    const short8* aSb8 = (const short8*)aS;
    const float4* oS4 = (const float4*)oS;
    for (int t = 0; t < EPB; ++t) {
        int e0 = (ebg * EPB + t) << 6;
        {   // stage h1: 64 rows x 16 short8
            const uint4* g = (const uint4*)(h1b + (size_t)e0 * 128);
            uint4* s = (uint4*)aS;
            for (int i = tid; i < 64 * 16; i += 256) {
                int r = i >> 4, c = i & 15;
                s[r * 17 + c] = g[i];
            }
        }
        {   // gather out[src] rows
            const float4* og = (const float4*)out;
            float4* s = (float4*)oS;
            for (int i = tid; i < 64 * 16; i += 256) {
                int r = i >> 4, q = i & 15;
                int src = ei[e0 + r];
                s[r * 17 + q] = og[(size_t)src * 16 + q];
            }
        }
        __syncthreads();
#pragma unroll
        for (int ee = 0; ee < 4; ++ee) {
            short8 bfr[4];
#pragma unroll
            for (int ks = 0; ks < 4; ++ks) bfr[ks] = aSb8[(ee * 16 + lm) * 17 + ks * 4 + lk];
            float4 ofr[4];
#pragma unroll
            for (int hi = 0; hi < 4; ++hi) ofr[hi] = oS4[(ee * 16 + lm) * 17 + hi * 4 + lk];
            float p = 0.0f;
#pragma unroll
            for (int hi = 0; hi < 4; ++hi) {
                f32x4 acc = (f32x4){0.f, 0.f, 0.f, 0.f};
#pragma unroll
                for (int ks = 0; ks < 4; ++ks)
                    acc = __builtin_amdgcn_mfma_f32_16x16x32_bf16(afr[hi][ks], bfr[ks], acc, 0, 0, 0);
                p += (acc[0] + bb[hi][0]) * ofr[hi].x + (acc[1] + bb[hi][1]) * ofr[hi].y +
                     (acc[2] + bb[hi][2]) * ofr[hi].z + (acc[3] + bb[hi][3]) * ofr[hi].w;
            }
            p += __shfl_xor(p, 16);
            p += __shfl_xor(p, 32);
            if (lk == 0) msg[(size_t)(e0 + ee * 16 + lm) * 64 + kt] = p;
        }
        __syncthreads();
    }
}

// ---------------- CSR aggregate + deg-normalize: agg[n][k] = mean over in-edges ----------------
__global__ __launch_bounds__(256) void k_agg(const int* __restrict__ rowptr,
                                             const int* __restrict__ csr,
                                             const float* __restrict__ msg,
                                             float* __restrict__ agg) {
    int node = (blockIdx.x << 2) + (threadIdx.x >> 6);
    int lane = threadIdx.x & 63;
    int b = rowptr[node], e_ = rowptr[node + 1];
    float s = 0.0f;
    for (int i = b; i < e_; ++i) {
        int e = csr[i];
        s += msg[(size_t)e * 64 + lane];
    }
    float d = fmaxf((float)(e_ - b), 1.0f);
    agg[(size_t)node * 64 + lane] = s / d;
}

// ---------------- fused node update: 1 wave = 16 nodes; root GEMM + m + GRU ----------------
__global__ __launch_bounds__(64) void k_node_fused(
    float* __restrict__ out, const float* __restrict__ agg,
    const __hip_bfloat16* __restrict__ crTb, const float* __restrict__ cb,
    const __hip_bfloat16* __restrict__ wihb, const __hip_bfloat16* __restrict__ whhb,
    const float* __restrict__ bih, const float* __restrict__ bhh) {
    __shared__ __align__(16) float Xf[16 * 68];
    __shared__ __align__(16) short Xb[16 * 72];
    __shared__ __align__(16) short Mb[16 * 72];
    int n0 = blockIdx.x << 4;
    int lane = threadIdx.x;
    {
        int r = lane >> 2, q = lane & 3;
        const float4* gv = (const float4*)(out + (size_t)(n0 + r) * 64);
        float4 v[4];
#pragma unroll
        for (int i = 0; i < 4; ++i) v[i] = gv[q * 4 + i];
        float4* sv = (float4*)Xf;
#pragma unroll
        for (int i = 0; i < 4; ++i) sv[r * 17 + q * 4 + i] = v[i];
        __hip_bfloat16* xb = (__hip_bfloat16*)Xb;
        const float* vf = (const float*)v;
#pragma unroll
        for (int i = 0; i < 16; ++i) xb[r * 72 + q * 16 + i] = __float2bfloat16(vf[i]);
    }
    __syncthreads();
    int lm = lane & 15, lk = lane >> 4;
    const short8* Xb8 = (const short8*)Xb;
    short8 ax[2];
#pragma unroll
    for (int ks = 0; ks < 2; ++ks) ax[ks] = Xb8[lm * 9 + ks * 4 + lk];
    const short8* Bc = (const short8*)crTb;
    f32x4 accr[4];
#pragma unroll
    for (int ci = 0; ci < 4; ++ci) accr[ci] = (f32x4){0.f, 0.f, 0.f, 0.f};
#pragma unroll
    for (int ks = 0; ks < 2; ++ks)
#pragma unroll
        for (int ci = 0; ci < 4; ++ci) {
            short8 b = Bc[(ci * 16 + lm) * 8 + ks * 4 + lk];
            accr[ci] = __builtin_amdgcn_mfma_f32_16x16x32_bf16(ax[ks], b, accr[ci], 0, 0, 0);
        }
    __hip_bfloat16* mb = (__hip_bfloat16*)Mb;
#pragma unroll
    for (int ci = 0; ci < 4; ++ci) {
        int col = ci * 16 + lm;
        float cbv = cb[col];
#pragma unroll
        for (int j = 0; j < 4; ++j) {
            int row = lk * 4 + j;
            int n = n0 + row;
            float a = agg[(size_t)n * 64 + col];
            float m = fmaxf(a + accr[ci][j] + cbv, 0.f);
            mb[row * 72 + col] = __float2bfloat16(m);
        }
    }
    __syncthreads();
    short8 am[2];
#pragma unroll
    for (int ks = 0; ks < 2; ++ks) am[ks] = ((const short8*)Mb)[lm * 9 + ks * 4 + lk];
    const short8* Bi = (const short8*)wihb;
    const short8* Bh = (const short8*)whhb;
    f32x4 gi[12], gh[12];
#pragma unroll
    for (int ci = 0; ci < 12; ++ci) {
        gi[ci] = (f32x4){0.f, 0.f, 0.f, 0.f};
        gh[ci] = (f32x4){0.f, 0.f, 0.f, 0.f};
    }
#pragma unroll
    for (int ks = 0; ks < 2; ++ks)
#pragma unroll
        for (int ci = 0; ci < 12; ++ci) {
            short8 bi = Bi[(ci * 16 + lm) * 8 + ks * 4 + lk];
            short8 bh = Bh[(ci * 16 + lm) * 8 + ks * 4 + lk];
            gi[ci] = __builtin_amdgcn_mfma_f32_16x16x32_bf16(am[ks], bi, gi[ci], 0, 0, 0);
            gh[ci] = __builtin_amdgcn_mfma_f32_16x16x32_bf16(ax[ks], bh, gh[ci], 0, 0, 0);
        }
#pragma unroll
    for (int ci = 0; ci < 4; ++ci) {
        int col = ci * 16 + lm;
        float bir = bih[col], biz = bih[64 + col], bin = bih[128 + col];
        float bhr = bhh[col], bhz = bhh[64 + col], bhn = bhh[128 + col];
#pragma unroll
        for (int j = 0; j < 4; ++j) {
            int row = lk * 4 + j;
            int n = n0 + row;
            float r = sigmoidf_(gi[ci][j] + bir + gh[ci][j] + bhr);
            float z = sigmoidf_(gi[ci + 4][j] + biz + gh[ci + 4][j] + bhz);
            float nn = tanhf(gi[ci + 8][j] + bin + r * (gh[ci + 8][j] + bhn));
            float hold = Xf[row * 68 + col];
            out[(size_t)n * 64 + col] = (1.f - z) * nn + z * hold;
        }
    }
}

// ---------------- Set2Set (6 steps) + memory LSTM ----------------
__global__ __launch_bounds__(64) void k_s2s(const float* __restrict__ out,
                                            const float* __restrict__ wih, const float* __restrict__ whh,
                                            const float* __restrict__ bih, const float* __restrict__ bhh,
                                            const float* __restrict__ mwih, const float* __restrict__ mbih,
                                            const float* __restrict__ mbhh,
                                            float* __restrict__ dout, float* __restrict__ hx_buf) {
    int g = blockIdx.x;
    int lane = threadIdx.x;
    __shared__ __align__(16) float os[NPG][65];
    __shared__ __align__(16) float q[128];
    __shared__ __align__(16) float hsS[64];
    __shared__ __align__(16) float aS[NPG];
    for (int n = 0; n < NPG; ++n) os[n][lane] = out[(size_t)(g * NPG + n) * 64 + lane];
    q[lane] = 0.0f;
    q[64 + lane] = 0.0f;
    hsS[lane] = 0.0f;
    float cs = 0.0f;
    __syncthreads();
    const float4* qv = (const float4*)q;
    const float4* hv = (const float4*)hsS;
    for (int step = 0; step < 6; ++step) {
        float gate[4];
#pragma unroll
        for (int gg = 0; gg < 4; ++gg) {
            int j = gg * 64 + lane;
            const float4* wr = (const float4*)(wih + (size_t)j * 128);
            const float4* vr = (const float4*)(whh + (size_t)j * 64);
            float s = bih[j] + bhh[j];
#pragma unroll 8
            for (int i = 0; i < 32; ++i) s += dot4(qv[i], wr[i]);
#pragma unroll 8
            for (int i = 0; i < 16; ++i) s += dot4(hv[i], vr[i]);
            gate[gg] = s;
        }
        cs = sigmoidf_(gate[1]) * cs + sigmoidf_(gate[0]) * tanhf(gate[2]);
        float hsv = sigmoidf_(gate[3]) * tanhf(cs);
        __syncthreads();
        hsS[lane] = hsv;
        __syncthreads();
        float e_n = -INFINITY;
        if (lane < NPG) {
            float s = 0.0f;
            for (int h = 0; h < 64; ++h) s += os[lane][h] * hsS[h];
            e_n = s;
        }
        float mx = e_n;
#pragma unroll
        for (int off = 32; off; off >>= 1) mx = fmaxf(mx, __shfl_xor(mx, off));
        float ex = (lane < NPG) ? __expf(e_n - mx) : 0.0f;
        float sm = ex;
#pragma unroll
        for (int off = 32; off; off >>= 1) sm += __shfl_xor(sm, off);
        if (lane < NPG) aS[lane] = ex / sm;
        __syncthreads();
        float r = 0.0f;
        for (int n = 0; n < NPG; ++n) r += aS[n] * os[n][lane];
        __syncthreads();
        q[lane] = hsv;
        q[64 + lane] = r;
        __syncthreads();
    }
    float gate[4];
#pragma unroll
    for (int gg = 0; gg < 4; ++gg) {
        int j = gg * 64 + lane;
        const float4* wr = (const float4*)(mwih + (size_t)j * 128);
        float s = mbih[j] + mbhh[j];
#pragma unroll 8
        for (int i = 0; i < 32; ++i) s += dot4(qv[i], wr[i]);
        gate[gg] = s;
    }
    float cx = sigmoidf_(gate[0]) * tanhf(gate[2]);
    float hx = sigmoidf_(gate[3]) * tanhf(cx);
    dout[30000 + g * 64 + lane] = hx;
    dout[62000 + g * 64 + lane] = cx;
    hx_buf[g * 64 + lane] = hx;
}

// ---------------- final MLP over torsions ----------------
__global__ __launch_bounds__(256) void k_mlp(const float* __restrict__ out,
                                             const float* __restrict__ hx_buf,
                                             const int* __restrict__ nrbidx,
                                             const int* __restrict__ nonring,
                                             const float* __restrict__ w1, const float* __restrict__ b1,
                                             const float* __restrict__ w2, const float* __restrict__ b2,
                                             float* __restrict__ logits) {
    __shared__ __align__(16) float feat[4][320];
    __shared__ __align__(16) float hid[4][64];
    int w = threadIdx.x >> 6, lane = threadIdx.x & 63;
    int t = (blockIdx.x << 2) + w;
    int g = nrbidx[t];
    feat[w][lane] = hx_buf[g * 64 + lane];
#pragma unroll
    for (int i = 0; i < 4; ++i) {
        int node = nonring[t * 4 + i];
        feat[w][64 + i * 64 + lane] = out[(size_t)node * 64 + lane];
    }
    __syncthreads();
    const float4* fv = (const float4*)feat[w];
    const float4* wr = (const float4*)(w1 + (size_t)lane * 320);
    float s = b1[lane];
#pragma unroll 8
    for (int i = 0; i < 80; ++i) s += dot4(fv[i], wr[i]);
    hid[w][lane] = fmaxf(s, 0.0f);
    __syncthreads();
    if (lane < ACT) {
        const float* hr = hid[w];
        const float* w2r = w2 + lane * 64;
        float s2 = b2[lane];
#pragma unroll 8
        for (int k = 0; k < 64; ++k) s2 += hr[k] * w2r[k];
        logits[t * ACT + lane] = s2;
    }
}

static inline size_t align256(size_t x) { return (x + 255) & ~(size_t)255; }

extern "C" void kernel_launch(void* const* d_in, const int* in_sizes, int n_in,
                              void* d_out, int out_size, void* d_ws, size_t ws_size,
                              hipStream_t stream) {
    const float* x         = (const float*)d_in[0];
    const float* edge_attr = (const float*)d_in[1];
    const int*   edge_index= (const int*)d_in[2];
    const int*   nrbidx    = (const int*)d_in[4];
    const int*   nonring   = (const int*)d_in[5];
    const float* lin0_w    = (const float*)d_in[6];
    const float* lin0_b    = (const float*)d_in[7];
    const float* enn_w1    = (const float*)d_in[8];
    const float* enn_b1    = (const float*)d_in[9];
    const float* enn_w2    = (const float*)d_in[10];
    const float* enn_b2    = (const float*)d_in[11];
    const float* conv_root = (const float*)d_in[12];
    const float* conv_bias = (const float*)d_in[13];
    const float* gru_wih   = (const float*)d_in[14];
    const float* gru_whh   = (const float*)d_in[15];
    const float* gru_bih   = (const float*)d_in[16];
    const float* gru_bhh   = (const float*)d_in[17];
    const float* s2s_wih   = (const float*)d_in[18];
    const float* s2s_whh   = (const float*)d_in[19];
    const float* s2s_bih   = (const float*)d_in[20];
    const float* s2s_bhh   = (const float*)d_in[21];
    const float* mem_wih   = (const float*)d_in[22];
    const float* mem_bih   = (const float*)d_in[24];
    const float* mem_bhh   = (const float*)d_in[25];
    const float* mlp_w1    = (const float*)d_in[26];
    const float* mlp_b1    = (const float*)d_in[27];
    const float* mlp_w2    = (const float*)d_in[28];
    const float* mlp_b2    = (const float*)d_in[29];
    float* dout = (float*)d_out;

    char* ws = (char*)d_ws;
    size_t off = 0;
    float* out_buf = (float*)(ws + off); off = align256(off + (size_t)N_NODES * 64 * 4);
    float* agg     = (float*)(ws + off); off = align256(off + (size_t)N_NODES * 64 * 4);
    float* msg     = (float*)(ws + off); off = align256(off + (size_t)N_EDGES * 64 * 4);
    __hip_bfloat16* h1b  = (__hip_bfloat16*)(ws + off); off = align256(off + (size_t)N_EDGES * 128 * 2);
    __hip_bfloat16* w2pb = (__hip_bfloat16*)(ws + off); off = align256(off + (size_t)4096 * 128 * 2);
    __hip_bfloat16* b2pb = (__hip_bfloat16*)(ws + off); off = align256(off + 4096 * 2);
    int* degi      = (int*)(ws + off); off = align256(off + N_NODES * 4);
    int* rowptr    = (int*)(ws + off); off = align256(off + (N_NODES + 1) * 4);
    int* cursor    = (int*)(ws + off); off = align256(off + N_NODES * 4);
    int* csr       = (int*)(ws + off); off = align256(off + N_EDGES * 4);
    float* hx_buf  = (float*)(ws + off); off = align256(off + (size_t)N_GRAPHS * 64 * 4);
    __hip_bfloat16* wihb = (__hip_bfloat16*)(ws + off); off = align256(off + 192 * 64 * 2);
    __hip_bfloat16* whhb = (__hip_bfloat16*)(ws + off); off = align256(off + 192 * 64 * 2);
    __hip_bfloat16* crTb = (__hip_bfloat16*)(ws + off); off = align256(off + 64 * 64 * 2);
    if (ws_size < off) return;  // ~33 MB needed

    k_lin0<<<(N_NODES * 64) / 256, 256, 0, stream>>>(x, lin0_w, lin0_b, out_buf);
    k_h1<<<(N_EDGES * 128) / 256, 256, 0, stream>>>(edge_attr, enn_w1, enn_b1, h1b);
    k_prep<<<(4096 * 128) / 256, 256, 0, stream>>>(enn_w2, enn_b2, w2pb, b2pb);
    k_prep2<<<112, 256, 0, stream>>>(conv_root, gru_wih, gru_whh, crTb, wihb, whhb);
    hipMemsetAsync(degi, 0, N_NODES * 4, stream);
    k_deg<<<(N_EDGES + 255) / 256, 256, 0, stream>>>(edge_index, degi);
    k_scan<<<1, 256, 0, stream>>>(degi, rowptr, cursor);
    k_fill<<<(N_EDGES + 255) / 256, 256, 0, stream>>>(edge_index, cursor, csr);
    for (int it = 0; it < 6; ++it) {
        k_edge_msg<<<125 * 16, 256, 0, stream>>>(edge_index, out_buf, h1b, w2pb, b2pb, msg);
        k_agg<<<N_NODES / 4, 256, 0, stream>>>(rowptr, csr, msg, agg);
        k_node_fused<<<N_NODES / 16, 64, 0, stream>>>(out_buf, agg, crTb, conv_bias,
                                                      wihb, whhb, gru_bih, gru_bhh);
    }
    k_s2s<<<N_GRAPHS, 64, 0, stream>>>(out_buf, s2s_wih, s2s_whh, s2s_bih, s2s_bhh,
                                       mem_wih, mem_bih, mem_bhh, dout, hx_buf);
    k_mlp<<<N_TORS / 4, 256, 0, stream>>>(out_buf, hx_buf, nrbidx, nonring,
                                          mlp_w1, mlp_b1, mlp_w2, mlp_b2, dout);
}